// Round 1
// baseline (182.329 us; speedup 1.0000x reference)
//
#include <hip/hip_runtime.h>
#include <math.h>

// Problem constants (from reference):
//   B=8, R=50 (rafs has 2R=100 channels), C=150, H=W=128, N=4096, K=192
#define KPTS   192
#define RDIM   50
#define HDIM   128
#define WDIM   128
#define NREL   4096
#define CDIM   150
#define LOSS_W 0.1f

__global__ __launch_bounds__(KPTS) void relation_loss_kernel(
    const float* __restrict__ rafs,      // (B, 2R, H, W)
    const float* __restrict__ heatmaps,  // (B, C, H, W)
    const int*   __restrict__ rels,      // (N, 8): bi, scls, sy, sx, ocls, oy, ox, pred
    float* __restrict__ out)             // scalar loss (pre-zeroed)
{
    const int n = blockIdx.x;
    const int k = threadIdx.x;

    const int* r = rels + n * 8;
    const int bi   = r[0];
    const int scls = r[1];
    const int sy   = r[2];
    const int sx   = r[3];
    const int ocls = r[4];
    const int oy   = r[5];
    const int ox   = r[6];
    const int pred = r[7];

    const float dx = (float)(ox - sx);
    const float dy = (float)(oy - sy);
    const float norms = sqrtf(dx * dx + dy * dy);
    const float ux = dx / norms;
    const float uy = dy / norms;
    const int   num = (int)ceilf(norms);
    const float denom = (float)((num - 1) > 1 ? (num - 1) : 1);

    const float oxf = (float)ox, oyf = (float)oy;
    const float sxmox = (float)(sx - ox);
    const float symoy = (float)(sy - oy);

    float dot  = 0.0f;
    int   vcnt = 0;

    if (k < num) {
        const float t  = (float)k / denom;
        const int   px = (int)rintf(oxf + t * sxmox);
        const int   py = (int)rintf(oyf + t * symoy);
        bool dup = false;
        if (k > 0) {
            const float tp  = (float)(k - 1) / denom;
            const int   pxp = (int)rintf(oxf + tp * sxmox);
            const int   pyp = (int)rintf(oyf + tp * symoy);
            dup = (px == pxp) && (py == pyp);
        }
        if (!dup) {
            // raf reshaped (B, R, 2, H, W) aliases rafs (B, 2R, H, W):
            // raf[bi][pred][c][py][px] = rafs[bi][2*pred + c][py][px]
            const size_t base =
                (((size_t)bi * (2 * RDIM) + (size_t)(2 * pred)) * HDIM + (size_t)py) * WDIM + (size_t)px;
            float vx = rafs[base];
            float vy = rafs[base + (size_t)HDIM * WDIM];
            vx = fminf(fmaxf(vx, -1.0f), 1.0f);
            vy = fminf(fmaxf(vy, -1.0f), 1.0f);
            dot  = vx * ux + vy * uy;
            vcnt = 1;
        }
    }

    // Reduce over the 192-thread block: wave64 shuffle tree, then LDS across 3 waves.
    #pragma unroll
    for (int off = 32; off > 0; off >>= 1) {
        dot  += __shfl_down(dot,  off, 64);
        vcnt += __shfl_down(vcnt, off, 64);
    }

    __shared__ float s_dot[KPTS / 64];
    __shared__ int   s_cnt[KPTS / 64];
    const int wave = threadIdx.x >> 6;
    const int lane = threadIdx.x & 63;
    if (lane == 0) { s_dot[wave] = dot; s_cnt[wave] = vcnt; }
    __syncthreads();

    if (threadIdx.x == 0) {
        float sdot = s_dot[0] + s_dot[1] + s_dot[2];
        int   cnt  = s_cnt[0] + s_cnt[1] + s_cnt[2];
        float integral = sdot / (float)cnt;            // cnt >= 1 always (k=0 valid)
        integral = fminf(fmaxf(integral, 0.0f), 1.0f);
        const float subj = heatmaps[(((size_t)bi * CDIM + (size_t)scls) * HDIM + (size_t)sy) * WDIM + (size_t)sx];
        const float obj  = heatmaps[(((size_t)bi * CDIM + (size_t)ocls) * HDIM + (size_t)oy) * WDIM + (size_t)ox];
        const float rs   = subj * obj * integral;
        const float logp = logf(fmaxf(rs, 1e-12f));
        atomicAdd(out, logp * (-LOSS_W / (float)NREL));
    }
}

extern "C" void kernel_launch(void* const* d_in, const int* in_sizes, int n_in,
                              void* d_out, int out_size, void* d_ws, size_t ws_size,
                              hipStream_t stream) {
    const float* rafs     = (const float*)d_in[0];
    const float* heatmaps = (const float*)d_in[1];
    const int*   rels     = (const int*)d_in[2];
    float*       out      = (float*)d_out;

    // Harness poisons d_out (0xAA) before every timed replay — zero it on-stream.
    hipMemsetAsync(out, 0, (size_t)out_size * sizeof(float), stream);

    relation_loss_kernel<<<NREL, KPTS, 0, stream>>>(rafs, heatmaps, rels, out);
}

// Round 2
// 138.033 us; speedup vs baseline: 1.3209x; 1.3209x over previous
//
#include <hip/hip_runtime.h>
#include <math.h>

// Problem constants (from reference):
//   B=8, R=50 (rafs has 2R=100 channels), C=150, H=W=128, N=4096, K=192
#define KPTS   192
#define RDIM   50
#define HDIM   128
#define WDIM   128
#define NREL   4096
#define CDIM   150
#define LOSS_W 0.1f
#define WPB    4          // waves (relations) per block
#define BLK    (WPB * 64)

// Stage 1: one wave per relation. Lane l covers samples k = l, l+64, l+128.
// Writes per-relation logp to ws[rel]. No atomics.
__global__ __launch_bounds__(BLK) void relation_partial_kernel(
    const float* __restrict__ rafs,      // (B, 2R, H, W)
    const float* __restrict__ heatmaps,  // (B, C, H, W)
    const int*   __restrict__ rels,      // (N, 8)
    float* __restrict__ ws)              // (N,) per-relation logp
{
    const int wave = threadIdx.x >> 6;
    const int lane = threadIdx.x & 63;
    const int rel  = blockIdx.x * WPB + wave;

    const int* r = rels + rel * 8;
    const int bi   = r[0];
    const int scls = r[1];
    const int sy   = r[2];
    const int sx   = r[3];
    const int ocls = r[4];
    const int oy   = r[5];
    const int ox   = r[6];
    const int pred = r[7];

    const float dx = (float)(ox - sx);
    const float dy = (float)(oy - sy);
    const float norms = sqrtf(dx * dx + dy * dy);
    const float ux = dx / norms;
    const float uy = dy / norms;
    const int   num = (int)ceilf(norms);           // 1..180 < 192
    const float denom = (float)((num - 1) > 1 ? (num - 1) : 1);

    const float oxf = (float)ox, oyf = (float)oy;
    const float sxmox = (float)(sx - ox);
    const float symoy = (float)(sy - oy);

    const size_t rafbase =
        ((size_t)bi * (2 * RDIM) + (size_t)(2 * pred)) * (HDIM * WDIM);

    float dot  = 0.0f;
    int   vcnt = 0;

    #pragma unroll
    for (int s = 0; s < 3; ++s) {
        const int k = lane + 64 * s;
        if (k < num) {
            const float t  = (float)k / denom;
            const int   px = (int)rintf(oxf + t * sxmox);
            const int   py = (int)rintf(oyf + t * symoy);
            bool dup = false;
            if (k > 0) {
                const float tp  = (float)(k - 1) / denom;
                const int   pxp = (int)rintf(oxf + tp * sxmox);
                const int   pyp = (int)rintf(oyf + tp * symoy);
                dup = (px == pxp) && (py == pyp);
            }
            if (!dup) {
                const size_t off = (size_t)py * WDIM + (size_t)px;
                float vx = rafs[rafbase + off];
                float vy = rafs[rafbase + (size_t)(HDIM * WDIM) + off];
                vx = fminf(fmaxf(vx, -1.0f), 1.0f);
                vy = fminf(fmaxf(vy, -1.0f), 1.0f);
                dot  += vx * ux + vy * uy;
                vcnt += 1;
            }
        }
    }

    // Wave64 shuffle reduction.
    #pragma unroll
    for (int off = 32; off > 0; off >>= 1) {
        dot  += __shfl_down(dot,  off, 64);
        vcnt += __shfl_down(vcnt, off, 64);
    }

    if (lane == 0) {
        float integral = dot / (float)vcnt;          // vcnt >= 1 (k=0 always valid)
        integral = fminf(fmaxf(integral, 0.0f), 1.0f);
        const float subj = heatmaps[(((size_t)bi * CDIM + (size_t)scls) * HDIM + (size_t)sy) * WDIM + (size_t)sx];
        const float obj  = heatmaps[(((size_t)bi * CDIM + (size_t)ocls) * HDIM + (size_t)oy) * WDIM + (size_t)ox];
        const float rs   = subj * obj * integral;
        ws[rel] = logf(fmaxf(rs, 1e-12f));
    }
}

// Stage 2: deterministic sum of NREL partials -> scalar loss. One block.
__global__ __launch_bounds__(256) void reduce_kernel(
    const float* __restrict__ part,   // (NREL,)
    float* __restrict__ out)
{
    const int tid = threadIdx.x;
    float acc = 0.0f;
    #pragma unroll
    for (int j = 0; j < NREL / 256; ++j)
        acc += part[tid + j * 256];

    #pragma unroll
    for (int off = 32; off > 0; off >>= 1)
        acc += __shfl_down(acc, off, 64);

    __shared__ float s[4];
    const int wave = tid >> 6;
    const int lane = tid & 63;
    if (lane == 0) s[wave] = acc;
    __syncthreads();
    if (tid == 0) {
        const float total = s[0] + s[1] + s[2] + s[3];
        out[0] = total * (-LOSS_W / (float)NREL);
    }
}

extern "C" void kernel_launch(void* const* d_in, const int* in_sizes, int n_in,
                              void* d_out, int out_size, void* d_ws, size_t ws_size,
                              hipStream_t stream) {
    const float* rafs     = (const float*)d_in[0];
    const float* heatmaps = (const float*)d_in[1];
    const int*   rels     = (const int*)d_in[2];
    float*       out      = (float*)d_out;
    float*       part     = (float*)d_ws;

    relation_partial_kernel<<<NREL / WPB, BLK, 0, stream>>>(rafs, heatmaps, rels, part);
    reduce_kernel<<<1, 256, 0, stream>>>(part, out);
}

// Round 3
// 136.186 us; speedup vs baseline: 1.3388x; 1.0136x over previous
//
#include <hip/hip_runtime.h>
#include <math.h>

// Problem constants (from reference):
//   B=8, R=50 (rafs has 2R=100 channels), C=150, H=W=128, N=4096, K=192
#define KPTS   192
#define RDIM   50
#define HDIM   128
#define WDIM   128
#define NREL   4096
#define CDIM   150
#define LOSS_W 0.1f
#define WPB    4          // waves (relations) per block
#define BLK    (WPB * 64)

// Stage 1: one wave per relation. Lane l covers samples k = l, l+64, l+128.
// All wave-uniform fields forced scalar via readfirstlane so address math is
// SALU and loads use SGPR bases. Writes per-relation logp to ws[rel]. No atomics.
__global__ __launch_bounds__(BLK) void relation_partial_kernel(
    const float* __restrict__ rafs,      // (B, 2R, H, W)
    const float* __restrict__ heatmaps,  // (B, C, H, W)
    const int*   __restrict__ rels,      // (N, 8)
    float* __restrict__ ws)              // (N,) per-relation logp
{
    const int wave = threadIdx.x >> 6;
    const int lane = threadIdx.x & 63;
    const int rel  = blockIdx.x * WPB + wave;

    // Two 16B loads instead of eight 4B loads; then broadcast to SGPRs.
    const int4* r4 = (const int4*)(rels + (size_t)rel * 8);
    const int4 ra = r4[0];   // bi, scls, sy, sx
    const int4 rb = r4[1];   // ocls, oy, ox, pred
    const int bi   = __builtin_amdgcn_readfirstlane(ra.x);
    const int scls = __builtin_amdgcn_readfirstlane(ra.y);
    const int sy   = __builtin_amdgcn_readfirstlane(ra.z);
    const int sx   = __builtin_amdgcn_readfirstlane(ra.w);
    const int ocls = __builtin_amdgcn_readfirstlane(rb.x);
    const int oy   = __builtin_amdgcn_readfirstlane(rb.y);
    const int ox   = __builtin_amdgcn_readfirstlane(rb.z);
    const int pred = __builtin_amdgcn_readfirstlane(rb.w);

    // Issue subj/obj loads early (scalar addresses -> s_load path); latency
    // overlaps the whole sample loop. Only lane 0 consumes the values.
    const float subj = heatmaps[(((size_t)bi * CDIM + (size_t)scls) * HDIM + (size_t)sy) * WDIM + (size_t)sx];
    const float obj  = heatmaps[(((size_t)bi * CDIM + (size_t)ocls) * HDIM + (size_t)oy) * WDIM + (size_t)ox];

    const float dx = (float)(ox - sx);
    const float dy = (float)(oy - sy);
    const float norms = sqrtf(dx * dx + dy * dy);
    const float ux = dx / norms;
    const float uy = dy / norms;
    const int   num = (int)ceilf(norms);           // 1..180 < 192
    const float denom = (float)((num - 1) > 1 ? (num - 1) : 1);

    const float oxf = (float)ox, oyf = (float)oy;
    const float sxmox = (float)(sx - ox);
    const float symoy = (float)(sy - oy);

    const size_t rafbase =
        ((size_t)bi * (2 * RDIM) + (size_t)(2 * pred)) * (HDIM * WDIM);

    float dot  = 0.0f;
    int   vcnt = 0;

    #pragma unroll
    for (int s = 0; s < 3; ++s) {
        const int k = lane + 64 * s;
        if (k < num) {                               // exec-mask skip when no lane active
            const float t  = (float)k / denom;
            const int   px = (int)rintf(oxf + t * sxmox);
            const int   py = (int)rintf(oyf + t * symoy);
            bool dup = false;
            if (k > 0) {
                const float tp  = (float)(k - 1) / denom;
                const int   pxp = (int)rintf(oxf + tp * sxmox);
                const int   pyp = (int)rintf(oyf + tp * symoy);
                dup = (px == pxp) && (py == pyp);
            }
            if (!dup) {
                const size_t off = (size_t)py * WDIM + (size_t)px;
                float vx = rafs[rafbase + off];
                float vy = rafs[rafbase + (size_t)(HDIM * WDIM) + off];
                vx = fminf(fmaxf(vx, -1.0f), 1.0f);
                vy = fminf(fmaxf(vy, -1.0f), 1.0f);
                dot  += vx * ux + vy * uy;
                vcnt += 1;
            }
        }
    }

    // Wave64 shuffle reduction.
    #pragma unroll
    for (int off = 32; off > 0; off >>= 1) {
        dot  += __shfl_down(dot,  off, 64);
        vcnt += __shfl_down(vcnt, off, 64);
    }

    if (lane == 0) {
        float integral = dot / (float)vcnt;          // vcnt >= 1 (k=0 always valid)
        integral = fminf(fmaxf(integral, 0.0f), 1.0f);
        const float rs = subj * obj * integral;
        ws[rel] = logf(fmaxf(rs, 1e-12f));
    }
}

// Stage 2: deterministic sum of NREL partials -> scalar loss. One block.
__global__ __launch_bounds__(256) void reduce_kernel(
    const float* __restrict__ part,   // (NREL,)
    float* __restrict__ out)
{
    const int tid = threadIdx.x;
    float acc = 0.0f;
    #pragma unroll
    for (int j = 0; j < NREL / 256; ++j)
        acc += part[tid + j * 256];

    #pragma unroll
    for (int off = 32; off > 0; off >>= 1)
        acc += __shfl_down(acc, off, 64);

    __shared__ float s[4];
    const int wave = tid >> 6;
    const int lane = tid & 63;
    if (lane == 0) s[wave] = acc;
    __syncthreads();
    if (tid == 0) {
        const float total = s[0] + s[1] + s[2] + s[3];
        out[0] = total * (-LOSS_W / (float)NREL);
    }
}

extern "C" void kernel_launch(void* const* d_in, const int* in_sizes, int n_in,
                              void* d_out, int out_size, void* d_ws, size_t ws_size,
                              hipStream_t stream) {
    const float* rafs     = (const float*)d_in[0];
    const float* heatmaps = (const float*)d_in[1];
    const int*   rels     = (const int*)d_in[2];
    float*       out      = (float*)d_out;
    float*       part     = (float*)d_ws;

    relation_partial_kernel<<<NREL / WPB, BLK, 0, stream>>>(rafs, heatmaps, rels, part);
    reduce_kernel<<<1, 256, 0, stream>>>(part, out);
}